// Round 3
// baseline (228.713 us; speedup 1.0000x reference)
//
#include <hip/hip_runtime.h>
#include <math.h>

#define BSZ    4
#define NTOK   6400      // 40*160
#define DMODEL 256
#define NHEAD  8
#define HDIM   32
#define NPTS   9
#define HSP    40
#define WSP    160
#define KDIM   256
#define MTOT   (BSZ*NTOK)   // 25600

typedef short  short8  __attribute__((ext_vector_type(8)));
typedef float  floatx4 __attribute__((ext_vector_type(4)));
typedef float  f32x2   __attribute__((ext_vector_type(2)));

__device__ __forceinline__ ushort f2bf(float f) {
    uint u = __float_as_uint(f);
    u = (u + 0x7FFFu + ((u >> 16) & 1u)) >> 16;   // RNE
    return (ushort)u;
}

// unpack 8 packed bf16 (uint4) -> 4 x f32x2 (pairs, channel order preserved)
__device__ __forceinline__ void unpack8v(uint4 u, f32x2* f) {
    f[0].x = __uint_as_float(u.x << 16); f[0].y = __uint_as_float(u.x & 0xFFFF0000u);
    f[1].x = __uint_as_float(u.y << 16); f[1].y = __uint_as_float(u.y & 0xFFFF0000u);
    f[2].x = __uint_as_float(u.z << 16); f[2].y = __uint_as_float(u.z & 0xFFFF0000u);
    f[3].x = __uint_as_float(u.w << 16); f[3].y = __uint_as_float(u.w & 0xFFFF0000u);
}

// dot of 8 bf16 (packed in uint4) with q2[4] (f32x2 pairs) -> scalar
__device__ __forceinline__ float dot8(uint4 u, const f32x2* q2) {
    f32x2 a; a.x = 0.f; a.y = 0.f;
    f32x2 t;
    t.x = __uint_as_float(u.x << 16); t.y = __uint_as_float(u.x & 0xFFFF0000u);
    a += t * q2[0];
    t.x = __uint_as_float(u.y << 16); t.y = __uint_as_float(u.y & 0xFFFF0000u);
    a += t * q2[1];
    t.x = __uint_as_float(u.z << 16); t.y = __uint_as_float(u.z & 0xFFFF0000u);
    a += t * q2[2];
    t.x = __uint_as_float(u.w << 16); t.y = __uint_as_float(u.w & 0xFFFF0000u);
    a += t * q2[3];
    return a.x + a.y;
}

#define AS1C(p) ((const __attribute__((address_space(1))) void*)(p))
#define AS3(p)  ((__attribute__((address_space(3))) void*)(p))

// ---------------------------------------------------------------------------
// All fp32->bf16 casts in one launch. Block = 1024 elems.
// Builds the fused weight buffer wf (1024 rows x 256 k, bf16):
//   rows [0,256)=Wq | [256,400)=Woff | [400,512)=zero pad | [512,1024)=Wkv
// ranges: x 6400 | Wq 64 | Woff 36 | zero 28 | Wkv 128 | Wout 64 => 6720 blocks
// ---------------------------------------------------------------------------
__global__ __launch_bounds__(256) void cast_all(
    const float* __restrict__ x,   const float* __restrict__ Wq,
    const float* __restrict__ Woff,const float* __restrict__ Wkv,
    const float* __restrict__ Wout,
    ushort* __restrict__ xb, ushort* __restrict__ wf, ushort* __restrict__ woutb)
{
    const int bid = blockIdx.x;
    if (bid >= 6500 && bid < 6528) {           // zero-fill pad rows 400..511
        const int i = (bid - 6500) * 1024 + threadIdx.x * 4;
        ushort4 z; z.x = 0; z.y = 0; z.z = 0; z.w = 0;
        *(ushort4*)(wf + 400 * 256 + i) = z;
        return;
    }
    const float* src; ushort* dst; int base;
    if      (bid < 6400) { src = x;    dst = xb;              base = bid; }
    else if (bid < 6464) { src = Wq;   dst = wf;              base = bid - 6400; }
    else if (bid < 6500) { src = Woff; dst = wf + 256 * 256;  base = bid - 6464; }
    else if (bid < 6656) { src = Wkv;  dst = wf + 512 * 256;  base = bid - 6528; }
    else                 { src = Wout; dst = woutb;           base = bid - 6656; }
    const int i = base * 1024 + threadIdx.x * 4;
    float4 v = *(const float4*)(src + i);
    ushort4 o;
    o.x = f2bf(v.x); o.y = f2bf(v.y); o.z = f2bf(v.z); o.w = f2bf(v.w);
    *(ushort4*)(dst + i) = o;
}

// ---------------------------------------------------------------------------
// Full-K single-barrier GEMM.  K=256 is tiny: stage the ENTIRE A k-extent
// (128 rows x 256 k x bf16 = 64 KB) via global_load_lds with ONE barrier,
// then run all 128 MFMAs/wave with no further syncs.  B (weights, <=512 KB,
// reused by 200 m-blocks -> L2-hot) is read directly from global inside the
// MFMA loop so the compiler can pipeline it freely.
//
// LDS layout: 4 chunks of [128 rows][8 granules x 16B], XOR-swizzled:
//   LDS[row][s] = Global[row][s ^ (row&7)]   (slot granularity 16 B)
// achieved by pre-swizzling the global SOURCE lane address (g_src =
// (lane&7)^(lane>>3)) while the global_load_lds dest stays linear.
// Reads use gsw = (g ^ (row&7)) -> rows spread across all 8 slots.
//
// XCD swizzle (bijective, grid % 8 == 0): all NBN n-blocks of one m-panel
// land on one XCD -> A panel fetched from HBM exactly once.
//
// MODE 0: fused q/off/kv epilogue (N=1024, grid 1600)
// MODE 1: out projection, fp32 store (N=256, grid 400)
// ---------------------------------------------------------------------------
template <int MODE>
__global__ __launch_bounds__(256) void gemm_fullk(
    const ushort* __restrict__ Xb,
    const ushort* __restrict__ Wf,
    const float* __restrict__ bq, const float* __restrict__ boff,
    const float* __restrict__ bkv,
    ushort* __restrict__ qb, float* __restrict__ off,
    ushort* __restrict__ kfb, ushort* __restrict__ vfb,
    float* __restrict__ Yout)
{
    constexpr int NBN = (MODE == 0) ? 8 : 2;   // n-blocks per m-panel
    __shared__ ushort As[4 * 128 * 64];        // 64 KB

    const int tid = threadIdx.x;
    const int bid = blockIdx.x;
    const int xcd = bid & 7;
    const int j   = bid >> 3;
    const int block_n = (j & (NBN - 1)) * 128;
    const int block_m = (xcd * 25 + j / NBN) * 128;

    const int wave = tid >> 6, lane = tid & 63;
    const int wm = (wave >> 1) * 64, wn = (wave & 1) * 64;
    const int l15 = lane & 15, quad = lane >> 4;

    // ---- stage full-K A tile, swizzled source / linear dest ----
    const int r8   = lane >> 3;            // row within 8-row group
    const int gsrc = (lane & 7) ^ r8;      // pre-swizzled source granule
    #pragma unroll
    for (int kc = 0; kc < 4; ++kc) {
        #pragma unroll
        for (int i = 0; i < 4; ++i) {
            const int rl = wave * 32 + i * 8;          // 8-aligned local row base
            const ushort* src = Xb + (size_t)(block_m + rl + r8) * KDIM
                                   + kc * 64 + gsrc * 8;
            ushort* dst = As + kc * (128 * 64) + rl * 64;
            __builtin_amdgcn_global_load_lds(AS1C(src), AS3(dst), 16, 0, 0);
        }
    }
    __syncthreads();   // the ONLY barrier

    floatx4 acc[4][4];
    #pragma unroll
    for (int i = 0; i < 4; ++i)
        #pragma unroll
        for (int jj = 0; jj < 4; ++jj) {
            acc[i][jj][0] = 0.f; acc[i][jj][1] = 0.f;
            acc[i][jj][2] = 0.f; acc[i][jj][3] = 0.f;
        }

    #pragma unroll
    for (int ks = 0; ks < 8; ++ks) {
        short8 af[4], bfr[4];
        #pragma unroll
        for (int f = 0; f < 4; ++f) {
            const int rowa = wm + f * 16 + l15;
            const int gsw  = (((ks & 1) * 4 + quad) ^ (l15 & 7));
            af[f]  = *(const short8*)(As + (ks >> 1) * (128 * 64) + rowa * 64 + gsw * 8);
            bfr[f] = *(const short8*)(Wf + (size_t)(block_n + wn + f * 16 + l15) * KDIM
                                         + ks * 32 + quad * 8);
        }
        #pragma unroll
        for (int fm = 0; fm < 4; ++fm)
            #pragma unroll
            for (int fn = 0; fn < 4; ++fn)
                acc[fm][fn] = __builtin_amdgcn_mfma_f32_16x16x32_bf16(
                    af[fm], bfr[fn], acc[fm][fn], 0, 0, 0);
    }

    // ---- epilogue: C/D layout col=lane&15, row=quad*4+reg ----
    #pragma unroll
    for (int fn = 0; fn < 4; ++fn) {
        const int col = block_n + wn + fn * 16 + l15;
        float bcol;
        if (MODE == 1) {
            bcol = bq[col];
        } else {
            if      (col < 256) bcol = bq[col];
            else if (col < 400) bcol = boff[col - 256];
            else if (col < 512) bcol = 0.f;
            else                bcol = bkv[col - 512];
        }
        #pragma unroll
        for (int fm = 0; fm < 4; ++fm) {
            #pragma unroll
            for (int r = 0; r < 4; ++r) {
                const int row = block_m + wm + fm * 16 + quad * 4 + r;
                const float val = acc[fm][fn][r] + bcol;
                if (MODE == 1) {
                    Yout[(size_t)row * DMODEL + col] = val;
                } else {
                    if (col < 256) {
                        qb[(size_t)row * DMODEL + col] = f2bf(val);
                    } else if (col < 400) {
                        off[(size_t)row * 144 + (col - 256)] = tanhf(val) * 4.0f;
                    } else if (col >= 512) {
                        const int c2 = col - 512;
                        const int bb = row / NTOK, nn = row % NTOK;
                        const int hh = (c2 & 255) >> 5, cc = c2 & 31;
                        const size_t o = (((size_t)(bb * NHEAD + hh)) * NTOK + nn) * HDIM + cc;
                        if (c2 < 256) kfb[o] = f2bf(val);
                        else          vfb[o] = f2bf(val);
                    }
                }
            }
        }
    }
}

// ---------------------------------------------------------------------------
// Deformable sampling + online-softmax attention, grouped two-phase.
// Wave = 2 tokens x 8 heads x 4 lanes; each lane owns 8 channels (16B loads).
// Points in 3 groups of 3: 12 K-corner gathers batched, one softmax update
// per group, 12 V-corner gathers batched. Packed f32x2 math.
// ---------------------------------------------------------------------------
__global__ __launch_bounds__(256) void deform_attn(
    const ushort* __restrict__ qb,    // (M,256) bf16
    const float* __restrict__ off,    // (M,144) fp32 (tanh*4 applied)
    const ushort* __restrict__ kfb,   // (B*H,N,32) bf16
    const ushort* __restrict__ vfb,
    ushort* __restrict__ attnb)       // (M,256) bf16
{
    const int lane = threadIdx.x & 63;
    const int token = blockIdx.x * 8 + (threadIdx.x >> 6) * 2 + (lane >> 5);
    const int h = (lane >> 2) & 7, lc = lane & 3;
    const int b = token / NTOK, n = token % NTOK;

    const uint4 qu = *(const uint4*)(qb + (size_t)token * DMODEL + h * HDIM + lc * 8);
    f32x2 q2[4]; unpack8v(qu, q2);

    const float* ob = off + (size_t)token * 144 + h * (NPTS * 2);
    const float bx = (float)(n % WSP), by = (float)(n / WSP);
    const ushort* kbase = kfb + (size_t)(b * NHEAD + h) * NTOK * HDIM + lc * 8;
    const ushort* vbase = vfb + (size_t)(b * NHEAD + h) * NTOK * HDIM + lc * 8;

    float m = -INFINITY, s = 0.f;
    f32x2 o2[4];
    #pragma unroll
    for (int i = 0; i < 4; ++i) { o2[i].x = 0.f; o2[i].y = 0.f; }

    #pragma unroll
    for (int g = 0; g < 3; ++g) {
        int   idx[3][4];
        float wt[3][4];
        #pragma unroll
        for (int jj = 0; jj < 3; ++jj) {
            const int p = g * 3 + jj;
            const float2 of = *(const float2*)(ob + 2 * p);
            const float sx = bx + of.x, sy = by + of.y;
            const float fx0 = floorf(sx), fy0 = floorf(sy);
            const float wx1 = sx - fx0, wx0 = 1.0f - wx1;
            const float wy1 = sy - fy0, wy0 = 1.0f - wy1;
            const int ix0 = (int)fx0, iy0 = (int)fy0;
            const int ix1 = ix0 + 1, iy1 = iy0 + 1;
            const bool vx0 = (ix0 >= 0) & (ix0 <= WSP - 1);
            const bool vx1 = (ix1 >= 0) & (ix1 <= WSP - 1);
            const bool vy0 = (iy0 >= 0) & (iy0 <= HSP - 1);
            const bool vy1 = (iy1 >= 0) & (iy1 <= HSP - 1);
            const int cx0 = min(max(ix0, 0), WSP - 1);
            const int cx1 = min(max(ix1, 0), WSP - 1);
            const int cy0 = min(max(iy0, 0), HSP - 1);
            const int cy1 = min(max(iy1, 0), HSP - 1);
            wt[jj][0] = wx0 * wy0 * (float)(vx0 && vy0);
            wt[jj][1] = wx1 * wy0 * (float)(vx1 && vy0);
            wt[jj][2] = wx0 * wy1 * (float)(vx0 && vy1);
            wt[jj][3] = wx1 * wy1 * (float)(vx1 && vy1);
            idx[jj][0] = (cy0 * WSP + cx0) * HDIM;
            idx[jj][1] = (cy0 * WSP + cx1) * HDIM;
            idx[jj][2] = (cy1 * WSP + cx0) * HDIM;
            idx[jj][3] = (cy1 * WSP + cx1) * HDIM;
        }

        // --- K phase: 12 gathers batched, 3 logits ---
        float l[3];
        #pragma unroll
        for (int jj = 0; jj < 3; ++jj) {
            const uint4 k0 = *(const uint4*)(kbase + idx[jj][0]);
            const uint4 k1 = *(const uint4*)(kbase + idx[jj][1]);
            const uint4 k2 = *(const uint4*)(kbase + idx[jj][2]);
            const uint4 k3 = *(const uint4*)(kbase + idx[jj][3]);
            float part = wt[jj][0] * dot8(k0, q2) + wt[jj][1] * dot8(k1, q2)
                       + wt[jj][2] * dot8(k2, q2) + wt[jj][3] * dot8(k3, q2);
            part += __shfl_xor(part, 1, 64);
            part += __shfl_xor(part, 2, 64);
            l[jj] = part * 0.17677669529663687f;   // 32^-0.5
        }

        // --- one online-softmax update per group ---
        const float m1 = fmaxf(fmaxf(fmaxf(l[0], l[1]), l[2]), m);
        const float corr = __expf(m - m1);
        const float e0 = __expf(l[0] - m1);
        const float e1 = __expf(l[1] - m1);
        const float e2 = __expf(l[2] - m1);
        s = s * corr + e0 + e1 + e2;
        m = m1;
        const float e[3] = {e0, e1, e2};

        #pragma unroll
        for (int i = 0; i < 4; ++i) o2[i] *= corr;

        // --- V phase: 12 gathers batched, weighted accumulate ---
        #pragma unroll
        for (int jj = 0; jj < 3; ++jj) {
            #pragma unroll
            for (int c = 0; c < 4; ++c) {
                const uint4 vu = *(const uint4*)(vbase + idx[jj][c]);
                f32x2 vv[4]; unpack8v(vu, vv);
                const float ew = e[jj] * wt[jj][c];
                #pragma unroll
                for (int i = 0; i < 4; ++i) o2[i] += vv[i] * ew;
            }
        }
    }

    const float inv = 1.0f / s;
    uint4 ru;
    ru.x = (uint)f2bf(o2[0].x * inv) | ((uint)f2bf(o2[0].y * inv) << 16);
    ru.y = (uint)f2bf(o2[1].x * inv) | ((uint)f2bf(o2[1].y * inv) << 16);
    ru.z = (uint)f2bf(o2[2].x * inv) | ((uint)f2bf(o2[2].y * inv) << 16);
    ru.w = (uint)f2bf(o2[3].x * inv) | ((uint)f2bf(o2[3].y * inv) << 16);
    *(uint4*)(attnb + (size_t)token * DMODEL + h * HDIM + lc * 8) = ru;
}

// ---------------------------------------------------------------------------
extern "C" void kernel_launch(void* const* d_in, const int* in_sizes, int n_in,
                              void* d_out, int out_size, void* d_ws, size_t ws_size,
                              hipStream_t stream) {
    const float* x    = (const float*)d_in[0];
    const float* Wq   = (const float*)d_in[1];
    const float* bq   = (const float*)d_in[2];
    const float* Woff = (const float*)d_in[3];
    const float* boff = (const float*)d_in[4];
    const float* Wkv  = (const float*)d_in[5];
    const float* bkv  = (const float*)d_in[6];
    const float* Wout = (const float*)d_in[7];
    const float* bout = (const float*)d_in[8];

    // workspace layout (~68 MB)
    ushort* xb    = (ushort*)d_ws;                         // 6,553,600 us (aliased by attnb)
    ushort* qb    = xb + (size_t)MTOT * DMODEL;            // 6,553,600 us
    float*  off   = (float*)(qb + (size_t)MTOT * DMODEL);  // 3,686,400 f32
    ushort* kfb   = (ushort*)(off + (size_t)MTOT * 144);   // 6,553,600 us
    ushort* vfb   = kfb + (size_t)MTOT * DMODEL;           // 6,553,600 us
    ushort* wf    = vfb + (size_t)MTOT * DMODEL;           // 262,144 us (1024x256)
    ushort* woutb = wf + 262144;                           // 65,536 us
    ushort* attnb = xb;   // xb dead after gemm_fullk<0>

    cast_all<<<dim3(6720), dim3(256), 0, stream>>>(x, Wq, Woff, Wkv, Wout,
                                                   xb, wf, woutb);

    gemm_fullk<0><<<dim3(1600), dim3(256), 0, stream>>>(xb, wf, bq, boff, bkv,
                                                        qb, off, kfb, vfb, nullptr);

    deform_attn<<<dim3(3200), dim3(256), 0, stream>>>(qb, off, kfb, vfb, attnb);

    gemm_fullk<1><<<dim3(400), dim3(256), 0, stream>>>(attnb, woutb, bout,
                                                       nullptr, nullptr, nullptr,
                                                       nullptr, nullptr, nullptr,
                                                       (float*)d_out);
}

// Round 4
// 218.453 us; speedup vs baseline: 1.0470x; 1.0470x over previous
//
#include <hip/hip_runtime.h>
#include <math.h>

#define BSZ    4
#define NTOK   6400      // 40*160
#define DMODEL 256
#define NHEAD  8
#define HDIM   32
#define NPTS   9
#define HSP    40
#define WSP    160
#define KDIM   256
#define MTOT   (BSZ*NTOK)   // 25600

typedef short  short8  __attribute__((ext_vector_type(8)));
typedef float  floatx4 __attribute__((ext_vector_type(4)));
typedef float  f32x2   __attribute__((ext_vector_type(2)));

__device__ __forceinline__ ushort f2bf(float f) {
    uint u = __float_as_uint(f);
    u = (u + 0x7FFFu + ((u >> 16) & 1u)) >> 16;   // RNE
    return (ushort)u;
}

// unpack 8 packed bf16 (uint4) -> 4 x f32x2 (pairs, channel order preserved)
__device__ __forceinline__ void unpack8v(uint4 u, f32x2* f) {
    f[0].x = __uint_as_float(u.x << 16); f[0].y = __uint_as_float(u.x & 0xFFFF0000u);
    f[1].x = __uint_as_float(u.y << 16); f[1].y = __uint_as_float(u.y & 0xFFFF0000u);
    f[2].x = __uint_as_float(u.z << 16); f[2].y = __uint_as_float(u.z & 0xFFFF0000u);
    f[3].x = __uint_as_float(u.w << 16); f[3].y = __uint_as_float(u.w & 0xFFFF0000u);
}

// dot of 8 bf16 (packed in uint4) with q2[4] (f32x2 pairs) -> scalar
__device__ __forceinline__ float dot8(uint4 u, const f32x2* q2) {
    f32x2 a; a.x = 0.f; a.y = 0.f;
    f32x2 t;
    t.x = __uint_as_float(u.x << 16); t.y = __uint_as_float(u.x & 0xFFFF0000u);
    a += t * q2[0];
    t.x = __uint_as_float(u.y << 16); t.y = __uint_as_float(u.y & 0xFFFF0000u);
    a += t * q2[1];
    t.x = __uint_as_float(u.z << 16); t.y = __uint_as_float(u.z & 0xFFFF0000u);
    a += t * q2[2];
    t.x = __uint_as_float(u.w << 16); t.y = __uint_as_float(u.w & 0xFFFF0000u);
    a += t * q2[3];
    return a.x + a.y;
}

#define AS1C(p) ((const __attribute__((address_space(1))) void*)(p))
#define AS3(p)  ((__attribute__((address_space(3))) void*)(p))

// ---------------------------------------------------------------------------
// All fp32->bf16 casts in one launch. Block = 1024 elems.
// Builds the fused weight buffer wf (1024 rows x 256 k, bf16):
//   rows [0,256)=Wq | [256,400)=Woff | [400,512)=zero pad | [512,1024)=Wkv
// ranges: x 6400 | Wq 64 | Woff 36 | zero 28 | Wkv 128 | Wout 64 => 6720 blocks
// ---------------------------------------------------------------------------
__global__ __launch_bounds__(256) void cast_all(
    const float* __restrict__ x,   const float* __restrict__ Wq,
    const float* __restrict__ Woff,const float* __restrict__ Wkv,
    const float* __restrict__ Wout,
    ushort* __restrict__ xb, ushort* __restrict__ wf, ushort* __restrict__ woutb)
{
    const int bid = blockIdx.x;
    if (bid >= 6500 && bid < 6528) {           // zero-fill pad rows 400..511
        const int i = (bid - 6500) * 1024 + threadIdx.x * 4;
        ushort4 z; z.x = 0; z.y = 0; z.z = 0; z.w = 0;
        *(ushort4*)(wf + 400 * 256 + i) = z;
        return;
    }
    const float* src; ushort* dst; int base;
    if      (bid < 6400) { src = x;    dst = xb;              base = bid; }
    else if (bid < 6464) { src = Wq;   dst = wf;              base = bid - 6400; }
    else if (bid < 6500) { src = Woff; dst = wf + 256 * 256;  base = bid - 6464; }
    else if (bid < 6656) { src = Wkv;  dst = wf + 512 * 256;  base = bid - 6528; }
    else                 { src = Wout; dst = woutb;           base = bid - 6656; }
    const int i = base * 1024 + threadIdx.x * 4;
    float4 v = *(const float4*)(src + i);
    ushort4 o;
    o.x = f2bf(v.x); o.y = f2bf(v.y); o.z = f2bf(v.z); o.w = f2bf(v.w);
    *(ushort4*)(dst + i) = o;
}

// ---------------------------------------------------------------------------
// 2-phase double-buffered GEMM (guide T3 minimal template, measured 655-682 TF
// at K=1024): both A and B staged via global_load_lds; stage(t+1) issued
// BEFORE compute(t); ONE __syncthreads per K-step. BK=64 -> 4 K-steps, 3 of 4
// stage drains hidden under MFMA.
//
// LDS: 2 bufs x (A 16 KB + B 16 KB) = 64 KB.  Row = 64 ushorts = 128 B = 8
// slots of 16 B.  XOR swizzle LDS[row][s] = G[row][s ^ (row&7)]:
//   - stage: linear dest (base + lane*16B), source slot (lane&7)^(lane>>3)
//   - ds_read: slot (ks2*4+quad) ^ (l15&7)
// -> max 2-way bank aliasing (free, m136).
//
// XCD-bijective block map (proven r3: FETCH 52->8.9 MB): all NBN n-blocks of
// one m-panel on one XCD.
//
// MODE 0: N=1024 fused epilogue q/off/kv (grid 1600)
// MODE 1: N=256 fp32 out-projection    (grid 400)
// ---------------------------------------------------------------------------
template <int MODE>
__global__ __launch_bounds__(256) void gemm_2ph(
    const ushort* __restrict__ Xb,
    const ushort* __restrict__ Wf,
    const float* __restrict__ bq, const float* __restrict__ boff,
    const float* __restrict__ bkv,
    ushort* __restrict__ qb, float* __restrict__ off,
    ushort* __restrict__ kfb, ushort* __restrict__ vfb,
    float* __restrict__ Yout)
{
    constexpr int NBN = (MODE == 0) ? 8 : 2;   // n-blocks per m-panel
    __shared__ ushort As[2][128 * 64];         // 2 x 16 KB
    __shared__ ushort Bs[2][128 * 64];         // 2 x 16 KB

    const int tid = threadIdx.x;
    const int bid = blockIdx.x;
    const int xcd = bid & 7;
    const int j   = bid >> 3;
    const int block_n = (j % NBN) * 128;
    const int block_m = (xcd * 25 + j / NBN) * 128;

    const int wave = tid >> 6, lane = tid & 63;
    const int wm = (wave >> 1) * 64, wn = (wave & 1) * 64;
    const int l15 = lane & 15, quad = lane >> 4;

    // staging: per wave 4 insts for A + 4 for B; inst i covers 8 rows
    // (wave*32 + i*8); lane -> row +(lane>>3), dest slot (lane&7) (implicit
    // linear), source slot (lane&7)^(lane>>3).
    const int srow  = lane >> 3;                 // 0..7
    const int sslot = (lane & 7) ^ srow;         // pre-swizzled src slot

    floatx4 acc[4][4];
    #pragma unroll
    for (int i = 0; i < 4; ++i)
        #pragma unroll
        for (int jj = 0; jj < 4; ++jj) {
            acc[i][jj][0] = 0.f; acc[i][jj][1] = 0.f;
            acc[i][jj][2] = 0.f; acc[i][jj][3] = 0.f;
        }

    auto stage = [&](int buf, int kt) {
        #pragma unroll
        for (int i = 0; i < 4; ++i) {
            const int rb = wave * 32 + i * 8;
            const ushort* sa = Xb + (size_t)(block_m + rb + srow) * KDIM + kt + sslot * 8;
            const ushort* sb = Wf + (size_t)(block_n + rb + srow) * KDIM + kt + sslot * 8;
            __builtin_amdgcn_global_load_lds(AS1C(sa), AS3(&As[buf][rb * 64]), 16, 0, 0);
            __builtin_amdgcn_global_load_lds(AS1C(sb), AS3(&Bs[buf][rb * 64]), 16, 0, 0);
        }
    };

    auto compute = [&](int buf) {
        #pragma unroll
        for (int ks2 = 0; ks2 < 2; ++ks2) {
            short8 af[4], bfr[4];
            #pragma unroll
            for (int f = 0; f < 4; ++f) {
                const int ra = wm + f * 16 + l15;
                const int rbb = wn + f * 16 + l15;
                const int sl = (((ks2 * 4 + quad) ^ (l15 & 7))) * 8;
                af[f]  = *(const short8*)&As[buf][ra * 64 + sl];
                bfr[f] = *(const short8*)&Bs[buf][rbb * 64 + sl];
            }
            #pragma unroll
            for (int fm = 0; fm < 4; ++fm)
                #pragma unroll
                for (int fn = 0; fn < 4; ++fn)
                    acc[fm][fn] = __builtin_amdgcn_mfma_f32_16x16x32_bf16(
                        af[fm], bfr[fn], acc[fm][fn], 0, 0, 0);
        }
    };

    // prologue: stage tile 0, drain, barrier
    stage(0, 0);
    __syncthreads();
    // main: stage(t+1) BEFORE compute(t); one sync per step
    #pragma unroll
    for (int t = 0; t < 3; ++t) {
        stage((t + 1) & 1, (t + 1) * 64);
        compute(t & 1);
        __syncthreads();
    }
    compute(1);   // tail: tile 3 in buf 1

    // ---- epilogue: C/D layout col=lane&15, row=quad*4+reg ----
    #pragma unroll
    for (int fn = 0; fn < 4; ++fn) {
        const int col = block_n + wn + fn * 16 + l15;
        float bcol;
        if (MODE == 1) {
            bcol = bq[col];
        } else {
            if      (col < 256) bcol = bq[col];
            else if (col < 400) bcol = boff[col - 256];
            else if (col < 512) bcol = 0.f;
            else                bcol = bkv[col - 512];
        }
        #pragma unroll
        for (int fm = 0; fm < 4; ++fm) {
            #pragma unroll
            for (int r = 0; r < 4; ++r) {
                const int row = block_m + wm + fm * 16 + quad * 4 + r;
                const float val = acc[fm][fn][r] + bcol;
                if (MODE == 1) {
                    Yout[(size_t)row * DMODEL + col] = val;
                } else {
                    if (col < 256) {
                        qb[(size_t)row * DMODEL + col] = f2bf(val);
                    } else if (col < 400) {
                        off[(size_t)row * 144 + (col - 256)] = tanhf(val) * 4.0f;
                    } else if (col >= 512) {
                        const int c2 = col - 512;
                        const int bb = row / NTOK, nn = row % NTOK;
                        const int hh = (c2 & 255) >> 5, cc = c2 & 31;
                        const size_t o = (((size_t)(bb * NHEAD + hh)) * NTOK + nn) * HDIM + cc;
                        if (c2 < 256) kfb[o] = f2bf(val);
                        else          vfb[o] = f2bf(val);
                    }
                }
            }
        }
    }
}

// ---------------------------------------------------------------------------
// Deformable sampling + online-softmax attention, grouped two-phase.
// Wave = 2 tokens x 8 heads x 4 lanes; each lane owns 8 channels (16B loads).
// Points in 3 groups of 3: 12 K-corner gathers batched, one softmax update
// per group, 12 V-corner gathers batched. Packed f32x2 math.
// ---------------------------------------------------------------------------
__global__ __launch_bounds__(256) void deform_attn(
    const ushort* __restrict__ qb,    // (M,256) bf16
    const float* __restrict__ off,    // (M,144) fp32 (tanh*4 applied)
    const ushort* __restrict__ kfb,   // (B*H,N,32) bf16
    const ushort* __restrict__ vfb,
    ushort* __restrict__ attnb)       // (M,256) bf16
{
    const int lane = threadIdx.x & 63;
    const int token = blockIdx.x * 8 + (threadIdx.x >> 6) * 2 + (lane >> 5);
    const int h = (lane >> 2) & 7, lc = lane & 3;
    const int b = token / NTOK, n = token % NTOK;

    const uint4 qu = *(const uint4*)(qb + (size_t)token * DMODEL + h * HDIM + lc * 8);
    f32x2 q2[4]; unpack8v(qu, q2);

    const float* ob = off + (size_t)token * 144 + h * (NPTS * 2);
    const float bx = (float)(n % WSP), by = (float)(n / WSP);
    const ushort* kbase = kfb + (size_t)(b * NHEAD + h) * NTOK * HDIM + lc * 8;
    const ushort* vbase = vfb + (size_t)(b * NHEAD + h) * NTOK * HDIM + lc * 8;

    float m = -INFINITY, s = 0.f;
    f32x2 o2[4];
    #pragma unroll
    for (int i = 0; i < 4; ++i) { o2[i].x = 0.f; o2[i].y = 0.f; }

    #pragma unroll
    for (int g = 0; g < 3; ++g) {
        int   idx[3][4];
        float wt[3][4];
        #pragma unroll
        for (int jj = 0; jj < 3; ++jj) {
            const int p = g * 3 + jj;
            const float2 of = *(const float2*)(ob + 2 * p);
            const float sx = bx + of.x, sy = by + of.y;
            const float fx0 = floorf(sx), fy0 = floorf(sy);
            const float wx1 = sx - fx0, wx0 = 1.0f - wx1;
            const float wy1 = sy - fy0, wy0 = 1.0f - wy1;
            const int ix0 = (int)fx0, iy0 = (int)fy0;
            const int ix1 = ix0 + 1, iy1 = iy0 + 1;
            const bool vx0 = (ix0 >= 0) & (ix0 <= WSP - 1);
            const bool vx1 = (ix1 >= 0) & (ix1 <= WSP - 1);
            const bool vy0 = (iy0 >= 0) & (iy0 <= HSP - 1);
            const bool vy1 = (iy1 >= 0) & (iy1 <= HSP - 1);
            const int cx0 = min(max(ix0, 0), WSP - 1);
            const int cx1 = min(max(ix1, 0), WSP - 1);
            const int cy0 = min(max(iy0, 0), HSP - 1);
            const int cy1 = min(max(iy1, 0), HSP - 1);
            wt[jj][0] = wx0 * wy0 * (float)(vx0 && vy0);
            wt[jj][1] = wx1 * wy0 * (float)(vx1 && vy0);
            wt[jj][2] = wx0 * wy1 * (float)(vx0 && vy1);
            wt[jj][3] = wx1 * wy1 * (float)(vx1 && vy1);
            idx[jj][0] = (cy0 * WSP + cx0) * HDIM;
            idx[jj][1] = (cy0 * WSP + cx1) * HDIM;
            idx[jj][2] = (cy1 * WSP + cx0) * HDIM;
            idx[jj][3] = (cy1 * WSP + cx1) * HDIM;
        }

        // --- K phase: 12 gathers batched, 3 logits ---
        float l[3];
        #pragma unroll
        for (int jj = 0; jj < 3; ++jj) {
            const uint4 k0 = *(const uint4*)(kbase + idx[jj][0]);
            const uint4 k1 = *(const uint4*)(kbase + idx[jj][1]);
            const uint4 k2 = *(const uint4*)(kbase + idx[jj][2]);
            const uint4 k3 = *(const uint4*)(kbase + idx[jj][3]);
            float part = wt[jj][0] * dot8(k0, q2) + wt[jj][1] * dot8(k1, q2)
                       + wt[jj][2] * dot8(k2, q2) + wt[jj][3] * dot8(k3, q2);
            part += __shfl_xor(part, 1, 64);
            part += __shfl_xor(part, 2, 64);
            l[jj] = part * 0.17677669529663687f;   // 32^-0.5
        }

        // --- one online-softmax update per group ---
        const float m1 = fmaxf(fmaxf(fmaxf(l[0], l[1]), l[2]), m);
        const float corr = __expf(m - m1);
        const float e0 = __expf(l[0] - m1);
        const float e1 = __expf(l[1] - m1);
        const float e2 = __expf(l[2] - m1);
        s = s * corr + e0 + e1 + e2;
        m = m1;
        const float e[3] = {e0, e1, e2};

        #pragma unroll
        for (int i = 0; i < 4; ++i) o2[i] *= corr;

        // --- V phase: 12 gathers batched, weighted accumulate ---
        #pragma unroll
        for (int jj = 0; jj < 3; ++jj) {
            #pragma unroll
            for (int c = 0; c < 4; ++c) {
                const uint4 vu = *(const uint4*)(vbase + idx[jj][c]);
                f32x2 vv[4]; unpack8v(vu, vv);
                const float ew = e[jj] * wt[jj][c];
                #pragma unroll
                for (int i = 0; i < 4; ++i) o2[i] += vv[i] * ew;
            }
        }
    }

    const float inv = 1.0f / s;
    uint4 ru;
    ru.x = (uint)f2bf(o2[0].x * inv) | ((uint)f2bf(o2[0].y * inv) << 16);
    ru.y = (uint)f2bf(o2[1].x * inv) | ((uint)f2bf(o2[1].y * inv) << 16);
    ru.z = (uint)f2bf(o2[2].x * inv) | ((uint)f2bf(o2[2].y * inv) << 16);
    ru.w = (uint)f2bf(o2[3].x * inv) | ((uint)f2bf(o2[3].y * inv) << 16);
    *(uint4*)(attnb + (size_t)token * DMODEL + h * HDIM + lc * 8) = ru;
}

// ---------------------------------------------------------------------------
extern "C" void kernel_launch(void* const* d_in, const int* in_sizes, int n_in,
                              void* d_out, int out_size, void* d_ws, size_t ws_size,
                              hipStream_t stream) {
    const float* x    = (const float*)d_in[0];
    const float* Wq   = (const float*)d_in[1];
    const float* bq   = (const float*)d_in[2];
    const float* Woff = (const float*)d_in[3];
    const float* boff = (const float*)d_in[4];
    const float* Wkv  = (const float*)d_in[5];
    const float* bkv  = (const float*)d_in[6];
    const float* Wout = (const float*)d_in[7];
    const float* bout = (const float*)d_in[8];

    // workspace layout (~68 MB)
    ushort* xb    = (ushort*)d_ws;                         // 6,553,600 us (aliased by attnb)
    ushort* qb    = xb + (size_t)MTOT * DMODEL;            // 6,553,600 us
    float*  off   = (float*)(qb + (size_t)MTOT * DMODEL);  // 3,686,400 f32
    ushort* kfb   = (ushort*)(off + (size_t)MTOT * 144);   // 6,553,600 us
    ushort* vfb   = kfb + (size_t)MTOT * DMODEL;           // 6,553,600 us
    ushort* wf    = vfb + (size_t)MTOT * DMODEL;           // 262,144 us (1024x256)
    ushort* woutb = wf + 262144;                           // 65,536 us
    ushort* attnb = xb;   // xb dead after gemm_2ph<0>

    cast_all<<<dim3(6720), dim3(256), 0, stream>>>(x, Wq, Woff, Wkv, Wout,
                                                   xb, wf, woutb);

    gemm_2ph<0><<<dim3(1600), dim3(256), 0, stream>>>(xb, wf, bq, boff, bkv,
                                                      qb, off, kfb, vfb, nullptr);

    deform_attn<<<dim3(3200), dim3(256), 0, stream>>>(qb, off, kfb, vfb, attnb);

    gemm_2ph<1><<<dim3(400), dim3(256), 0, stream>>>(attnb, woutb, bout,
                                                     nullptr, nullptr, nullptr,
                                                     nullptr, nullptr, nullptr,
                                                     (float*)d_out);
}